// Round 6
// baseline (517.176 us; speedup 1.0000x reference)
//
#include <hip/hip_runtime.h>
#include <stdint.h>

#define N 8192
#define D 256

typedef __attribute__((ext_vector_type(4))) float f32x4;
typedef __attribute__((ext_vector_type(8))) short bf16x8;

__device__ __forceinline__ unsigned short f2bf(float f) {
    unsigned u = __float_as_uint(f);
    u += 0x7fff + ((u >> 16) & 1);           // RNE
    return (unsigned short)(u >> 16);
}
__device__ __forceinline__ float leaky(float x) {
    return fmaxf(x, 0.f) + 0.2f * fminf(x, 0.f);
}
// CK-style block_sync_lds: LDS-ordering barrier that does NOT drain vmcnt,
// so register-destination global prefetches stay in flight across it.
__device__ __forceinline__ void sync_lds() {
    asm volatile("s_waitcnt lgkmcnt(0)\n\ts_barrier" ::: "memory");
}

// ---------------- K0: compress adj (fp32 0/1) + diagonal into bitmask ----------------
__global__ __launch_bounds__(256) void k0_compress(const float* __restrict__ adj,
                                                   unsigned int* __restrict__ mask) {
    const size_t fbase = ((size_t)blockIdx.x * 256 + threadIdx.x) * 4;  // float index
    float4 v = *(const float4*)(adj + fbase);
    const int lane = threadIdx.x & 63;
    unsigned nib = (v.x > 0.f ? 1u : 0u) | (v.y > 0.f ? 2u : 0u) |
                   (v.z > 0.f ? 4u : 0u) | (v.w > 0.f ? 8u : 0u);
    unsigned word = nib << ((lane & 7) * 4);
    word |= __shfl_xor(word, 1);
    word |= __shfl_xor(word, 2);
    word |= __shfl_xor(word, 4);
    if ((lane & 7) == 0) {
        size_t widx = fbase >> 5;                 // word index; word covers 32 floats
        int r = (int)(widx >> 8);                 // 256 words per row
        int ww = (int)(widx & 255);
        if ((r >> 5) == ww) word |= 1u << (r & 31);   // diagonal
        mask[widx] = word;
    }
}

// ---------------- K1: Wh = x @ W (fp32), x staged in SGPRs (wave-uniform loads) ----------------
#define K1_BM 8
__global__ __launch_bounds__(256) void k1_gemm(const float* __restrict__ x,
                                               const float* __restrict__ W,
                                               float* __restrict__ Wh,
                                               unsigned short* __restrict__ WhT) {
    const int t = threadIdx.x;      // = output column
    const int r0 = blockIdx.x * K1_BM;
    float acc[K1_BM];
#pragma unroll
    for (int i = 0; i < K1_BM; ++i) acc[i] = 0.f;

    for (int k0 = 0; k0 < D; k0 += 8) {
        // x chunk: wave-uniform addresses -> scalar loads (no LDS, no barriers)
        float xs[K1_BM][8];
#pragma unroll
        for (int r = 0; r < K1_BM; ++r)
#pragma unroll
            for (int kk = 0; kk < 8; ++kk)
                xs[r][kk] = x[(size_t)(r0 + r) * D + k0 + kk];
#pragma unroll
        for (int kk = 0; kk < 8; ++kk) {
            float wv = W[(size_t)(k0 + kk) * D + t];
#pragma unroll
            for (int r = 0; r < K1_BM; ++r)
                acc[r] += xs[r][kk] * wv;
        }
    }
#pragma unroll
    for (int r = 0; r < K1_BM; ++r) Wh[(size_t)(r0 + r) * D + t] = acc[r];
    unsigned short pk[K1_BM];
#pragma unroll
    for (int r = 0; r < K1_BM; ++r) pk[r] = f2bf(acc[r]);
    *(uint4*)(WhT + (size_t)t * N + r0) = *(uint4*)&pk[0];
}

// ---------------- K2: e_src / e_dst (wave per row) ----------------
__global__ __launch_bounds__(256) void k2_edot(const float* __restrict__ Wh,
                                               const float* __restrict__ a,
                                               float* __restrict__ e_src,
                                               float* __restrict__ e_dst) {
    const int wave = threadIdx.x >> 6, lane = threadIdx.x & 63;
    const int row = blockIdx.x * 4 + wave;
    float4 wv = *(const float4*)(Wh + (size_t)row * D + lane * 4);
    float4 as = *(const float4*)(a + lane * 4);
    float4 ad = *(const float4*)(a + D + lane * 4);
    float ps = wv.x * as.x + wv.y * as.y + wv.z * as.z + wv.w * as.w;
    float pd = wv.x * ad.x + wv.y * ad.y + wv.z * ad.z + wv.w * ad.w;
#pragma unroll
    for (int m = 1; m < 64; m <<= 1) {
        ps += __shfl_xor(ps, m);
        pd += __shfl_xor(pd, m);
    }
    if (lane == 0) { e_src[row] = ps; e_dst[row] = pd; }
}

// ---------------- K3: maxdst = max(e_dst) ----------------
__global__ __launch_bounds__(256) void k3_max(const float* __restrict__ e_dst,
                                              float* __restrict__ maxdst) {
    __shared__ float red[4];
    const int t = threadIdx.x;
    float m = -3.4e38f;
    for (int i = t; i < N; i += 256) m = fmaxf(m, e_dst[i]);
#pragma unroll
    for (int msk = 1; msk < 64; msk <<= 1) m = fmaxf(m, __shfl_xor(m, msk));
    if ((t & 63) == 0) red[t >> 6] = m;
    __syncthreads();
    if (t == 0) *maxdst = fmaxf(fmaxf(red[0], red[1]), fmaxf(red[2], red[3]));
}

// ---------------- K4: masked softmax + PV matmul (bitmask adj, BK=128, j-split) ----------------
#define BM 64
#define BK 128
#define RB (N / BM)                 // 128 row-blocks
#define SPLITS 8                    // grid = RB*SPLITS = 1024
#define NITER ((N / SPLITS) / BK)   // 8
#define PSTRIDE 136                 // ushorts per P row (272 B)
__global__ __launch_bounds__(512, 4) void k4_main(const unsigned char* __restrict__ mask,
                                                  const unsigned short* __restrict__ WhT,
                                                  const float* __restrict__ e_src,
                                                  const float* __restrict__ e_dst,
                                                  const float* __restrict__ maxdst,
                                                  float* __restrict__ O_part,
                                                  float* __restrict__ l_part) {
    __shared__ unsigned short p_lds[2][BM][PSTRIDE];   // double-buffered P tile, 34.8 KB

    const int t = threadIdx.x;
    const int rb = blockIdx.x & (RB - 1);
    const int s  = blockIdx.x >> 7;          // RB = 128
    const int r0 = rb * BM;
    const int j0 = s * (N / SPLITS);

    // P-generation coords: 8 threads per row, 16 cols each
    const int pr = t >> 3;            // 0..63
    const int pcw = t & 7;            // 16-col lane within row slice
    const int pc = pcw * 16;          // 0..112
    const int gr = r0 + pr;

    const int w = t >> 6;             // wave 0..7 -> output cols w*32..w*32+31
    const int lane = t & 63;
    const int quad = lane >> 4, lo = lane & 15;

    const float md = *maxdst;
    const float es = e_src[gr];
    const float m = leaky(es + md);

    f32x4 acc[4][2];
#pragma unroll
    for (int mt = 0; mt < 4; ++mt)
#pragma unroll
        for (int nt = 0; nt < 2; ++nt)
            acc[mt][nt] = (f32x4){0.f, 0.f, 0.f, 0.f};
    float lsum = 0.f;

    // mask row slice: this thread's 2 bytes (16 bits) per iter at mrow[it*16]
    const unsigned char* mrow = mask + (size_t)gr * (N / 8) + (j0 >> 3) + pcw * 2;
    const float* ed_row = e_dst + j0 + pc;
    const unsigned short* wt_base = WhT + (size_t)(w * 32 + lo) * N + j0 + quad * 8;

    unsigned int mb;
    float4 edv[4];
    bf16x8 bfr[4][2];                 // [ks][nt]

    // ---- prologue: loads for tile 0 ----
    mb = *(const unsigned short*)(mrow);
#pragma unroll
    for (int j = 0; j < 4; ++j) edv[j] = *(const float4*)(ed_row + j * 4);
#pragma unroll
    for (int ks = 0; ks < 4; ++ks)
#pragma unroll
        for (int nt = 0; nt < 2; ++nt)
            bfr[ks][nt] = *(const bf16x8*)(wt_base + (size_t)nt * (16 * N) + ks * 32);

    auto stage = [&](int buf) {
        float ev[16];
#pragma unroll
        for (int j = 0; j < 4; ++j) {
            ev[j * 4 + 0] = edv[j].x; ev[j * 4 + 1] = edv[j].y;
            ev[j * 4 + 2] = edv[j].z; ev[j * 4 + 3] = edv[j].w;
        }
        unsigned short pk[16];
#pragma unroll
        for (int jj = 0; jj < 16; ++jj) {
            float e = leaky(es + ev[jj]);
            float p = ((mb >> jj) & 1u) ? __expf(e - m) : 0.f;
            lsum += p;
            pk[jj] = f2bf(p);
        }
        *(uint4*)&p_lds[buf][pr][pc] = *(uint4*)&pk[0];
        *(uint4*)&p_lds[buf][pr][pc + 8] = *(uint4*)&pk[8];
    };

    // stage(0), then prefetch mask/ed for tile 1
    stage(0);
    mb = *(const unsigned short*)(mrow + 16);
#pragma unroll
    for (int j = 0; j < 4; ++j) edv[j] = *(const float4*)(ed_row + BK + j * 4);
    sync_lds();

#pragma unroll 2
    for (int it = 0; it < NITER; ++it) {
        const int cb = it & 1, nb = cb ^ 1;

        // ---- MFMA on p_lds[cb] x bfr ----
#pragma unroll
        for (int ks = 0; ks < 4; ++ks) {
            bf16x8 afr[4];
#pragma unroll
            for (int mt = 0; mt < 4; ++mt)
                afr[mt] = *(const bf16x8*)&p_lds[cb][mt * 16 + lo][ks * 32 + quad * 8];
#pragma unroll
            for (int nt = 0; nt < 2; ++nt)
#pragma unroll
                for (int mt = 0; mt < 4; ++mt)
                    acc[mt][nt] = __builtin_amdgcn_mfma_f32_16x16x32_bf16(
                        afr[mt], bfr[ks][nt], acc[mt][nt], 0, 0, 0);
        }

        // ---- reissue B-fragment loads for it+1 (stay in flight across barrier) ----
        {
            const int itn = (it + 1 < NITER) ? it + 1 : NITER - 1;
#pragma unroll
            for (int ks = 0; ks < 4; ++ks)
#pragma unroll
                for (int nt = 0; nt < 2; ++nt)
                    bfr[ks][nt] = *(const bf16x8*)(wt_base + (size_t)nt * (16 * N) +
                                                   itn * BK + ks * 32);
        }

        // ---- stage(it+1) into p_lds[nb], prefetch mask/ed for it+2 ----
        if (it + 1 < NITER) {
            stage(nb);
            const int itn2 = (it + 2 < NITER) ? it + 2 : NITER - 1;
            mb = *(const unsigned short*)(mrow + itn2 * 16);
#pragma unroll
            for (int j = 0; j < 4; ++j)
                edv[j] = *(const float4*)(ed_row + itn2 * BK + j * 4);
        }
        sync_lds();
    }

    // ---- epilogue: reduce per-row partial l (8 threads per row) ----
#pragma unroll
    for (int msk = 1; msk < 8; msk <<= 1) lsum += __shfl_xor(lsum, msk);
    if ((t & 7) == 0) l_part[(size_t)s * N + gr] = lsum;

    // ---- epilogue: O_part via LDS transpose -> fully-coalesced float4 stores ----
    float* obuf = (float*)p_lds;
#pragma unroll
    for (int mt = 0; mt < 4; ++mt) {
        __syncthreads();
#pragma unroll
        for (int nt = 0; nt < 2; ++nt) {
            f32x4 v = acc[mt][nt];
            int col = w * 32 + nt * 16 + lo;
#pragma unroll
            for (int reg = 0; reg < 4; ++reg)
                obuf[(quad * 4 + reg) * 256 + col] = v[reg];
        }
        __syncthreads();
        const int orow = t >> 5;            // 0..15
        const int ocol = (t & 31) * 8;      // 0..248
        f32x4 o0 = *(const f32x4*)&obuf[orow * 256 + ocol];
        f32x4 o1 = *(const f32x4*)&obuf[orow * 256 + ocol + 4];
        float* dst = O_part + ((size_t)s * N + r0 + mt * 16 + orow) * D + ocol;
        *(f32x4*)dst = o0;
        *(f32x4*)(dst + 4) = o1;
    }
}

// ---------------- K5: reduce partials (float4), divide by l ----------------
__global__ __launch_bounds__(256) void k5_reduce(const float* __restrict__ O_part,
                                                 const float* __restrict__ l_part,
                                                 float* __restrict__ out) {
    const int idx = blockIdx.x * 256 + threadIdx.x;   // over N*D/4
    const int r = idx >> 6;                           // D/4 = 64 float4 per row
    float lsum = 0.f;
#pragma unroll
    for (int s = 0; s < SPLITS; ++s) lsum += l_part[(size_t)s * N + r];
    f32x4 o = (f32x4){0.f, 0.f, 0.f, 0.f};
#pragma unroll
    for (int s = 0; s < SPLITS; ++s)
        o += *(const f32x4*)(O_part + (size_t)s * N * D + (size_t)idx * 4);
    const float inv = 1.f / lsum;
    *(f32x4*)(out + (size_t)idx * 4) = o * inv;
}

// ---------------- launch ----------------
extern "C" void kernel_launch(void* const* d_in, const int* in_sizes, int n_in,
                              void* d_out, int out_size, void* d_ws, size_t ws_size,
                              hipStream_t stream) {
    const float* x   = (const float*)d_in[0];   // [N, D]
    const float* adj = (const float*)d_in[1];   // [N, N]
    const float* W   = (const float*)d_in[2];   // [D, D]
    const float* a   = (const float*)d_in[3];   // [2*D]
    float* out = (float*)d_out;

    // ws layout (~92 MB):
    char* ws = (char*)d_ws;
    float* Wh            = (float*)(ws);                         // 8 MB
    unsigned short* WhT  = (unsigned short*)(ws + 8388608);      // 4 MB
    float* e_src         = (float*)(ws + 12582912);              // 32 KB
    float* e_dst         = (float*)(ws + 12615680);              // 32 KB
    float* maxdst        = (float*)(ws + 12648448);              // 256 B
    float* l_part        = (float*)(ws + 12648704);              // 256 KB
    unsigned int* mask   = (unsigned int*)(ws + 13631488);       // 8 MB (N*N/8 bytes)
    float* O_part        = (float*)(ws + 25165824);              // 64 MB (SPLITS*N*D*4)

    k0_compress<<<N * N / 4 / 256, 256, 0, stream>>>(adj, mask);
    k1_gemm<<<N / K1_BM, 256, 0, stream>>>(x, W, Wh, WhT);
    k2_edot<<<N / 4, 256, 0, stream>>>(Wh, a, e_src, e_dst);
    k3_max<<<1, 256, 0, stream>>>(e_dst, maxdst);
    k4_main<<<RB * SPLITS, 512, 0, stream>>>((const unsigned char*)mask, WhT, e_src, e_dst,
                                             maxdst, O_part, l_part);
    k5_reduce<<<N * D / 4 / 256, 256, 0, stream>>>(O_part, l_part, out);
}

// Round 7
// 482.849 us; speedup vs baseline: 1.0711x; 1.0711x over previous
//
#include <hip/hip_runtime.h>
#include <stdint.h>

#define N 8192
#define D 256

typedef __attribute__((ext_vector_type(4))) float f32x4;
typedef __attribute__((ext_vector_type(8))) short bf16x8;

__device__ __forceinline__ unsigned short f2bf(float f) {
    unsigned u = __float_as_uint(f);
    u += 0x7fff + ((u >> 16) & 1);           // RNE
    return (unsigned short)(u >> 16);
}
__device__ __forceinline__ float bf2f(unsigned short h) {
    unsigned u = ((unsigned)h) << 16;
    return __uint_as_float(u);
}
__device__ __forceinline__ float leaky(float x) {
    return fmaxf(x, 0.f) + 0.2f * fminf(x, 0.f);
}
// CK-style block_sync_lds: LDS-ordering barrier that does NOT drain vmcnt.
__device__ __forceinline__ void sync_lds() {
    asm volatile("s_waitcnt lgkmcnt(0)\n\ts_barrier" ::: "memory");
}

// ---------------- K0: compress adj (fp32 0/1) + diagonal into bitmask ----------------
__global__ __launch_bounds__(256) void k0_compress(const float* __restrict__ adj,
                                                   unsigned int* __restrict__ mask) {
    const size_t fbase = ((size_t)blockIdx.x * 256 + threadIdx.x) * 4;  // float index
    float4 v = *(const float4*)(adj + fbase);
    const int lane = threadIdx.x & 63;
    unsigned nib = (v.x > 0.f ? 1u : 0u) | (v.y > 0.f ? 2u : 0u) |
                   (v.z > 0.f ? 4u : 0u) | (v.w > 0.f ? 8u : 0u);
    unsigned word = nib << ((lane & 7) * 4);
    word |= __shfl_xor(word, 1);
    word |= __shfl_xor(word, 2);
    word |= __shfl_xor(word, 4);
    if ((lane & 7) == 0) {
        size_t widx = fbase >> 5;
        int r = (int)(widx >> 8);
        int ww = (int)(widx & 255);
        if ((r >> 5) == ww) word |= 1u << (r & 31);   // diagonal
        mask[widx] = word;
    }
}

// ---------------- K1c: split x into bf16 hi/lo ----------------
__global__ __launch_bounds__(256) void k1c_x(const float* __restrict__ x,
                                             unsigned short* __restrict__ xhi,
                                             unsigned short* __restrict__ xlo) {
    const size_t idx = ((size_t)blockIdx.x * 256 + threadIdx.x) * 4;
    float4 v = *(const float4*)(x + idx);
    unsigned short h[4], l[4];
    float vv[4] = {v.x, v.y, v.z, v.w};
#pragma unroll
    for (int j = 0; j < 4; ++j) {
        h[j] = f2bf(vv[j]);
        l[j] = f2bf(vv[j] - bf2f(h[j]));
    }
    *(ushort4*)(xhi + idx) = *(ushort4*)h;
    *(ushort4*)(xlo + idx) = *(ushort4*)l;
}

// ---------------- K1w: transpose+split W into bf16 WT hi/lo [n][k] ----------------
__global__ __launch_bounds__(256) void k1w(const float* __restrict__ W,
                                           unsigned short* __restrict__ wthi,
                                           unsigned short* __restrict__ wtlo) {
    const int n = blockIdx.x;          // output row of WT
    const int k = threadIdx.x;
    float w = W[(size_t)k * D + n];    // W[k][n]
    unsigned short h = f2bf(w);
    unsigned short l = f2bf(w - bf2f(h));
    wthi[(size_t)n * D + k] = h;
    wtlo[(size_t)n * D + k] = l;
}

// ---------------- K1m: Wh = x@W via bf16x3 MFMA; writes WhT bf16 + e_src/e_dst ----------------
// BM=16 rows/block, 256 threads (4 waves); wave w covers cols w*64..w*64+63 (nt<4).
__global__ __launch_bounds__(256) void k1m(const unsigned short* __restrict__ xhi,
                                           const unsigned short* __restrict__ xlo,
                                           const unsigned short* __restrict__ wthi,
                                           const unsigned short* __restrict__ wtlo,
                                           const float* __restrict__ a,
                                           unsigned short* __restrict__ WhT,
                                           float* __restrict__ e_src,
                                           float* __restrict__ e_dst) {
    __shared__ float obuf[16 * 256];   // 16 KB staging

    const int t = threadIdx.x;
    const int r0 = blockIdx.x * 16;
    const int w = t >> 6;              // 0..3
    const int lane = t & 63;
    const int quad = lane >> 4, lo = lane & 15;

    const unsigned short* xh_row = xhi + (size_t)(r0 + lo) * D;
    const unsigned short* xl_row = xlo + (size_t)(r0 + lo) * D;

    f32x4 acc[4];
#pragma unroll
    for (int nt = 0; nt < 4; ++nt) acc[nt] = (f32x4){0.f, 0.f, 0.f, 0.f};

#pragma unroll
    for (int ks = 0; ks < 8; ++ks) {   // k chunks of 32
        const int kofs = ks * 32 + quad * 8;
        bf16x8 ah = *(const bf16x8*)(xh_row + kofs);
        bf16x8 al = *(const bf16x8*)(xl_row + kofs);
#pragma unroll
        for (int nt = 0; nt < 4; ++nt) {
            const int n = w * 64 + nt * 16 + lo;
            bf16x8 bh = *(const bf16x8*)(wthi + (size_t)n * D + kofs);
            bf16x8 bl = *(const bf16x8*)(wtlo + (size_t)n * D + kofs);
            acc[nt] = __builtin_amdgcn_mfma_f32_16x16x32_bf16(ah, bh, acc[nt], 0, 0, 0);
            acc[nt] = __builtin_amdgcn_mfma_f32_16x16x32_bf16(ah, bl, acc[nt], 0, 0, 0);
            acc[nt] = __builtin_amdgcn_mfma_f32_16x16x32_bf16(al, bh, acc[nt], 0, 0, 0);
        }
    }

    // WhT bf16 [n][r]: per (nt): 4 consecutive rows (quad*4+reg) at col n
#pragma unroll
    for (int nt = 0; nt < 4; ++nt) {
        const int n = w * 64 + nt * 16 + lo;
        unsigned short pk[4];
#pragma unroll
        for (int reg = 0; reg < 4; ++reg) pk[reg] = f2bf(acc[nt][reg]);
        *(ushort2*)(WhT + (size_t)n * N + r0 + quad * 4) = *(ushort2*)&pk[0];
        *(ushort2*)(WhT + (size_t)n * N + r0 + quad * 4 + 2) = *(ushort2*)&pk[2];
    }

    // stage full 16x256 block output to LDS (fp32) for e-dot
#pragma unroll
    for (int nt = 0; nt < 4; ++nt) {
        const int col = w * 64 + nt * 16 + lo;
#pragma unroll
        for (int reg = 0; reg < 4; ++reg)
            obuf[(quad * 4 + reg) * 256 + col] = acc[nt][reg];
    }
    __syncthreads();

    // e_src/e_dst: row = t>>4, 16 threads per row, 16 cols each
    const int row = t >> 4;
    const int c0 = (t & 15) * 16;
    float ps = 0.f, pd = 0.f;
#pragma unroll
    for (int j = 0; j < 4; ++j) {
        float4 wv = *(const float4*)&obuf[row * 256 + c0 + j * 4];
        float4 as = *(const float4*)(a + c0 + j * 4);
        float4 ad = *(const float4*)(a + D + c0 + j * 4);
        ps += wv.x * as.x + wv.y * as.y + wv.z * as.z + wv.w * as.w;
        pd += wv.x * ad.x + wv.y * ad.y + wv.z * ad.z + wv.w * ad.w;
    }
#pragma unroll
    for (int msk = 1; msk < 16; msk <<= 1) {
        ps += __shfl_xor(ps, msk);
        pd += __shfl_xor(pd, msk);
    }
    if ((t & 15) == 0) {
        e_src[r0 + row] = ps;
        e_dst[r0 + row] = pd;
    }
}

// ---------------- K3: maxdst = max(e_dst) ----------------
__global__ __launch_bounds__(256) void k3_max(const float* __restrict__ e_dst,
                                              float* __restrict__ maxdst) {
    __shared__ float red[4];
    const int t = threadIdx.x;
    float m = -3.4e38f;
    for (int i = t; i < N; i += 256) m = fmaxf(m, e_dst[i]);
#pragma unroll
    for (int msk = 1; msk < 64; msk <<= 1) m = fmaxf(m, __shfl_xor(m, msk));
    if ((t & 63) == 0) red[t >> 6] = m;
    __syncthreads();
    if (t == 0) *maxdst = fmaxf(fmaxf(red[0], red[1]), fmaxf(red[2], red[3]));
}

// ---------------- K4: masked softmax + PV matmul (bitmask adj, BK=64, j-split) ----------------
#define BM 64
#define BK 64
#define RB (N / BM)                 // 128 row-blocks
#define SPLITS 8                    // grid = RB*SPLITS = 1024
#define NITER ((N / SPLITS) / BK)   // 16
#define PSTRIDE 72                  // ushorts per P row (144 B)
__global__ __launch_bounds__(512, 4) void k4_main(const unsigned char* __restrict__ mask,
                                                  const unsigned short* __restrict__ WhT,
                                                  const float* __restrict__ e_src,
                                                  const float* __restrict__ e_dst,
                                                  const float* __restrict__ maxdst,
                                                  float* __restrict__ O_part,
                                                  float* __restrict__ l_part) {
    __shared__ unsigned short p_lds[2][BM][PSTRIDE];   // double-buffered P tile, 18.4 KB

    const int t = threadIdx.x;
    const int rb = blockIdx.x & (RB - 1);
    const int s  = blockIdx.x >> 7;          // RB = 128
    const int r0 = rb * BM;
    const int j0 = s * (N / SPLITS);

    const int pr = t >> 3;            // 0..63
    const int pcw = t & 7;
    const int pc = pcw * 8;           // 0..56
    const int gr = r0 + pr;

    const int w = t >> 6;             // wave 0..7 -> output cols w*32..w*32+31
    const int lane = t & 63;
    const int quad = lane >> 4, lo = lane & 15;

    const float md = *maxdst;
    const float es = e_src[gr];
    const float m = leaky(es + md);

    f32x4 acc[4][2];
#pragma unroll
    for (int mt = 0; mt < 4; ++mt)
#pragma unroll
        for (int nt = 0; nt < 2; ++nt)
            acc[mt][nt] = (f32x4){0.f, 0.f, 0.f, 0.f};
    float lsum = 0.f;

    const unsigned char* mrow = mask + (size_t)gr * (N / 8) + (j0 >> 3) + pcw;
    const float* ed_row = e_dst + j0 + pc;
    const unsigned short* wt_base = WhT + (size_t)(w * 32 + lo) * N + j0 + quad * 8;

    unsigned int mb;
    float4 edv0, edv1;
    bf16x8 bfr[2][2];                 // [ks2][nt]

    // ---- prologue: loads for tile 0 ----
    mb = mrow[0];
    edv0 = *(const float4*)(ed_row);
    edv1 = *(const float4*)(ed_row + 4);
#pragma unroll
    for (int ks2 = 0; ks2 < 2; ++ks2)
#pragma unroll
        for (int nt = 0; nt < 2; ++nt)
            bfr[ks2][nt] = *(const bf16x8*)(wt_base + (size_t)nt * (16 * N) + ks2 * 32);

    auto stage = [&](int buf) {
        float ev[8] = {edv0.x, edv0.y, edv0.z, edv0.w,
                       edv1.x, edv1.y, edv1.z, edv1.w};
        unsigned short pk[8];
#pragma unroll
        for (int jj = 0; jj < 8; ++jj) {
            float e = leaky(es + ev[jj]);
            float p = ((mb >> jj) & 1u) ? __expf(e - m) : 0.f;
            lsum += p;
            pk[jj] = f2bf(p);
        }
        *(uint4*)&p_lds[buf][pr][pc] = *(uint4*)pk;
    };

    stage(0);
    mb = mrow[8];
    edv0 = *(const float4*)(ed_row + BK);
    edv1 = *(const float4*)(ed_row + BK + 4);
    sync_lds();

#pragma unroll 2
    for (int it = 0; it < NITER; ++it) {
        const int cb = it & 1, nb = cb ^ 1;

#pragma unroll
        for (int ks2 = 0; ks2 < 2; ++ks2) {
            bf16x8 afr[4];
#pragma unroll
            for (int mt = 0; mt < 4; ++mt)
                afr[mt] = *(const bf16x8*)&p_lds[cb][mt * 16 + lo][ks2 * 32 + quad * 8];
#pragma unroll
            for (int nt = 0; nt < 2; ++nt)
#pragma unroll
                for (int mt = 0; mt < 4; ++mt)
                    acc[mt][nt] = __builtin_amdgcn_mfma_f32_16x16x32_bf16(
                        afr[mt], bfr[ks2][nt], acc[mt][nt], 0, 0, 0);
        }

        {
            const int itn = (it + 1 < NITER) ? it + 1 : NITER - 1;
#pragma unroll
            for (int ks2 = 0; ks2 < 2; ++ks2)
#pragma unroll
                for (int nt = 0; nt < 2; ++nt)
                    bfr[ks2][nt] = *(const bf16x8*)(wt_base + (size_t)nt * (16 * N) +
                                                    itn * BK + ks2 * 32);
        }

        if (it + 1 < NITER) {
            stage(nb);
            const int itn2 = (it + 2 < NITER) ? it + 2 : NITER - 1;
            mb = mrow[itn2 * 8];
            edv0 = *(const float4*)(ed_row + itn2 * BK);
            edv1 = *(const float4*)(ed_row + itn2 * BK + 4);
        }
        sync_lds();
    }

#pragma unroll
    for (int msk = 1; msk < 8; msk <<= 1) lsum += __shfl_xor(lsum, msk);
    if ((t & 7) == 0) l_part[(size_t)s * N + gr] = lsum;

    // O_part via LDS transpose -> coalesced float4 stores
    float* obuf = (float*)p_lds;
#pragma unroll
    for (int mt = 0; mt < 4; ++mt) {
        __syncthreads();
#pragma unroll
        for (int nt = 0; nt < 2; ++nt) {
            f32x4 v = acc[mt][nt];
            int col = w * 32 + nt * 16 + lo;
#pragma unroll
            for (int reg = 0; reg < 4; ++reg)
                obuf[(quad * 4 + reg) * 256 + col] = v[reg];
        }
        __syncthreads();
        const int orow = t >> 5;            // 0..15
        const int ocol = (t & 31) * 8;      // 0..248
        f32x4 o0 = *(const f32x4*)&obuf[orow * 256 + ocol];
        f32x4 o1 = *(const f32x4*)&obuf[orow * 256 + ocol + 4];
        float* dst = O_part + ((size_t)s * N + r0 + mt * 16 + orow) * D + ocol;
        *(f32x4*)dst = o0;
        *(f32x4*)(dst + 4) = o1;
    }
}

// ---------------- K5: reduce partials (float4), divide by l ----------------
__global__ __launch_bounds__(256) void k5_reduce(const float* __restrict__ O_part,
                                                 const float* __restrict__ l_part,
                                                 float* __restrict__ out) {
    const int idx = blockIdx.x * 256 + threadIdx.x;   // over N*D/4
    const int r = idx >> 6;
    float lsum = 0.f;
#pragma unroll
    for (int s = 0; s < SPLITS; ++s) lsum += l_part[(size_t)s * N + r];
    f32x4 o = (f32x4){0.f, 0.f, 0.f, 0.f};
#pragma unroll
    for (int s = 0; s < SPLITS; ++s)
        o += *(const f32x4*)(O_part + (size_t)s * N * D + (size_t)idx * 4);
    const float inv = 1.f / lsum;
    *(f32x4*)(out + (size_t)idx * 4) = o * inv;
}

// ---------------- launch ----------------
extern "C" void kernel_launch(void* const* d_in, const int* in_sizes, int n_in,
                              void* d_out, int out_size, void* d_ws, size_t ws_size,
                              hipStream_t stream) {
    const float* x   = (const float*)d_in[0];   // [N, D]
    const float* adj = (const float*)d_in[1];   // [N, N]
    const float* W   = (const float*)d_in[2];   // [D, D]
    const float* a   = (const float*)d_in[3];   // [2*D]
    float* out = (float*)d_out;

    // ws layout (~92 MB):
    char* ws = (char*)d_ws;
    unsigned short* xhi  = (unsigned short*)(ws);                // 4 MB
    unsigned short* xlo  = (unsigned short*)(ws + 4194304);      // 4 MB
    unsigned short* WhT  = (unsigned short*)(ws + 8388608);      // 4 MB
    unsigned short* wthi = (unsigned short*)(ws + 12582912);     // 128 KB
    unsigned short* wtlo = (unsigned short*)(ws + 12713984);     // 128 KB
    float* e_src         = (float*)(ws + 12845056);              // 32 KB
    float* e_dst         = (float*)(ws + 12877824);              // 32 KB
    float* maxdst        = (float*)(ws + 12910592);              // 256 B
    float* l_part        = (float*)(ws + 12910848);              // 256 KB
    unsigned int* mask   = (unsigned int*)(ws + 13631488);       // 8 MB (N*N/8 bytes)
    float* O_part        = (float*)(ws + 25165824);              // 64 MB (SPLITS*N*D*4)

    k0_compress<<<N * N / 4 / 256, 256, 0, stream>>>(adj, mask);
    k1c_x<<<N * D / 4 / 256, 256, 0, stream>>>(x, xhi, xlo);
    k1w<<<D, D, 0, stream>>>(W, wthi, wtlo);
    k1m<<<N / 16, 256, 0, stream>>>(xhi, xlo, wthi, wtlo, a, WhT, e_src, e_dst);
    k3_max<<<1, 256, 0, stream>>>(e_dst, maxdst);
    k4_main<<<RB * SPLITS, 512, 0, stream>>>((const unsigned char*)mask, WhT, e_src, e_dst,
                                             maxdst, O_part, l_part);
    k5_reduce<<<N * D / 4 / 256, 256, 0, stream>>>(O_part, l_part, out);
}